// Round 10
// baseline (264.679 us; speedup 1.0000x reference)
//
#include <hip/hip_runtime.h>
#include <float.h>
#include <math.h>

#define TOKS 16384
#define HDIM 4096
#define NEXP 64
#define BM   64            // tokens per block tile
#define NTILE (TOKS / BM)  // 256
#define WPE  262144        // u16 elems per w bf16 plane (64*4096)

typedef __attribute__((ext_vector_type(8)))  short short8v;  // 8 bf16 = one A/B frag
typedef __attribute__((ext_vector_type(16))) float f32x16;   // C/D frag

// Exact 3-way bf16 split by truncation: v = s1+s2+s3+eps, eps <= 2^-24*|v|.
__device__ __forceinline__ void split3(float v, unsigned& b1, unsigned& b2, unsigned& b3) {
  unsigned xb = __float_as_uint(v);
  b1 = xb >> 16;
  float r = v - __uint_as_float(xb & 0xFFFF0000u);
  unsigned rb = __float_as_uint(r);
  b2 = rb >> 16;
  float r2 = r - __uint_as_float(rb & 0xFFFF0000u);
  b3 = __float_as_uint(r2) >> 16;
}
__device__ __forceinline__ void cvt2(float a, float b, unsigned& o1, unsigned& o2, unsigned& o3) {
  unsigned a1, a2, a3, c1, c2, c3;
  split3(a, a1, a2, a3);
  split3(b, c1, c2, c3);
  o1 = a1 | (c1 << 16); o2 = a2 | (c2 << 16); o3 = a3 | (c3 << 16);
}

// ---- pre-kernel: w [64][4096] f32 -> 3 bf16 planes [3][64][4096] (row-major) ----
__global__ __launch_bounds__(256)
void wsplit_kernel(const float* __restrict__ wgt, unsigned short* __restrict__ wsp) {
  const int gid  = blockIdx.x * 256 + threadIdx.x;   // 32768 threads x 8 elems
  const int base = gid * 8;
  const float4 f0 = *(const float4*)(wgt + base);
  const float4 f1 = *(const float4*)(wgt + base + 4);
  uint4 q1, q2, q3;
  cvt2(f0.x, f0.y, q1.x, q2.x, q3.x);
  cvt2(f0.z, f0.w, q1.y, q2.y, q3.y);
  cvt2(f1.x, f1.y, q1.z, q2.z, q3.z);
  cvt2(f1.z, f1.w, q1.w, q2.w, q3.w);
  *(uint4*)(wsp + base)            = q1;
  *(uint4*)(wsp + WPE + base)      = q2;
  *(uint4*)(wsp + 2 * WPE + base)  = q3;
}

// ---- stage 1: LDS-free register-streaming MFMA ----
// grid (256 tiles, ks). Block 256 thr = 4 waves (wm=wv>>1 tok-half, we=wv&1
// exp-half); wave = 32 tok x 32 exp via mfma_f32_32x32x16_bf16.
// A-frag read DIRECTLY from global x (lane r: row wm*32+r, 8 contiguous k fp32,
// split in-reg); B-frag from pre-split bf16 planes (L2-resident, 16B/lane).
// No LDS, no barriers -> compiler software-pipelines freely; 4 waves/SIMD TLP.
// Numerics as passing R8: x1w1 into m0/m1 (alternating), 5 cross terms into c.
__global__ __launch_bounds__(256)
void router_mfma_kernel(const float* __restrict__ x,
                        const unsigned short* __restrict__ wsp,
                        float* __restrict__ part, int ks) {
  const int tid  = threadIdx.x;
  const int lane = tid & 63;
  const int wv   = tid >> 6;
  const int kt   = blockIdx.y;
  const int tokBase = blockIdx.x * BM;

  const int wm = wv >> 1, we = wv & 1;
  const int r  = lane & 31, h2 = lane >> 5;

  const int kSlice = HDIM / ks;
  const int kStart = kt * kSlice;
  const int nst    = kSlice / 16;      // k16-steps in this slice (even)

  const float*          xp = x   + (size_t)(tokBase + wm * 32 + r) * HDIM + kStart + h2 * 8;
  const unsigned short* bp = wsp + (size_t)(we * 32 + r) * HDIM + kStart + h2 * 8;

  f32x16 acc_m0, acc_m1, acc_c;
#pragma unroll
  for (int i = 0; i < 16; ++i) { acc_m0[i] = 0.f; acc_m1[i] = 0.f; acc_c[i] = 0.f; }

#define MFMA(a, b, c) __builtin_amdgcn_mfma_f32_32x32x16_bf16((a), (b), (c), 0, 0, 0)

  // one k16 step at float offset `off`; x1w1 -> macc, cross terms -> acc_c
#define STEP(macc, off) do { \
    const float4 xa_ = *(const float4*)(xp + (off)); \
    const float4 xb_ = *(const float4*)(xp + (off) + 4); \
    const short8v b1_ = *(const short8v*)(bp + (off)); \
    const short8v b2_ = *(const short8v*)(bp + WPE + (off)); \
    const short8v b3_ = *(const short8v*)(bp + 2 * WPE + (off)); \
    uint4 q1_, q2_, q3_; \
    cvt2(xa_.x, xa_.y, q1_.x, q2_.x, q3_.x); \
    cvt2(xa_.z, xa_.w, q1_.y, q2_.y, q3_.y); \
    cvt2(xb_.x, xb_.y, q1_.z, q2_.z, q3_.z); \
    cvt2(xb_.z, xb_.w, q1_.w, q2_.w, q3_.w); \
    const short8v a1_ = __builtin_bit_cast(short8v, q1_); \
    const short8v a2_ = __builtin_bit_cast(short8v, q2_); \
    const short8v a3_ = __builtin_bit_cast(short8v, q3_); \
    macc  = MFMA(a1_, b1_, macc); \
    acc_c = MFMA(a1_, b2_, acc_c); \
    acc_c = MFMA(a2_, b1_, acc_c); \
    acc_c = MFMA(a1_, b3_, acc_c); \
    acc_c = MFMA(a2_, b2_, acc_c); \
    acc_c = MFMA(a3_, b1_, acc_c); \
  } while (0)

  for (int s = 0; s < nst; s += 2) {
    STEP(acc_m0, 0);
    STEP(acc_m1, 16);
    xp += 32; bp += 32;
  }

  // partial logits [kt][tile][64 tok][64 exp] (C/D map: row=(reg&3)+8*(reg>>2)+4*h2)
  float* pp = part + ((size_t)kt * NTILE + blockIdx.x) * 4096;
#pragma unroll
  for (int reg = 0; reg < 16; ++reg) {
    const int rowf = (reg & 3) + 8 * (reg >> 2) + 4 * h2;
    pp[(wm * 32 + rowf) * 64 + we * 32 + r] = (acc_m0[reg] + acc_m1[reg]) + acc_c[reg];
  }
}

// ---- stage 2: sum ks partials + bias, top-8 + softmax. 1024 blocks x 64 thr ----
__global__ __launch_bounds__(64)
void reduce_topk_kernel(const float* __restrict__ part,
                        const float* __restrict__ bias,
                        float* __restrict__ out, int ks) {
  __shared__ __align__(16) float fin[1024];       // 16 tokens x 64 experts
  const int lane = threadIdx.x;                   // 0..63
  const int g    = blockIdx.x;                    // token group: tokens 16g..16g+15
  const int tile = g >> 2;
  const int rowBase = (g & 3) * 16;

  // thread covers flat [lane*16, lane*16+16) of the 16x64 tile
  const int row = lane >> 2;
  const int e0  = (lane & 3) * 16;
  const size_t off0 = (size_t)tile * 4096 + (rowBase + row) * 64 + e0;
  float4 s0 = make_float4(0.f, 0.f, 0.f, 0.f), s1 = s0, s2 = s0, s3 = s0;
  for (int kt = 0; kt < ks; ++kt) {
    const float* p = part + (size_t)kt * (NTILE * 4096) + off0;
    const float4 q0 = *(const float4*)(p);
    const float4 q1 = *(const float4*)(p + 4);
    const float4 q2 = *(const float4*)(p + 8);
    const float4 q3 = *(const float4*)(p + 12);
    s0.x += q0.x; s0.y += q0.y; s0.z += q0.z; s0.w += q0.w;
    s1.x += q1.x; s1.y += q1.y; s1.z += q1.z; s1.w += q1.w;
    s2.x += q2.x; s2.y += q2.y; s2.z += q2.z; s2.w += q2.w;
    s3.x += q3.x; s3.y += q3.y; s3.z += q3.z; s3.w += q3.w;
  }
  *(float4*)(&fin[lane * 16])      = s0;
  *(float4*)(&fin[lane * 16 + 4])  = s1;
  *(float4*)(&fin[lane * 16 + 8])  = s2;
  *(float4*)(&fin[lane * 16 + 12]) = s3;
  __syncthreads();

  for (int tt = 0; tt < 16; ++tt) {
    float v = fin[tt * 64 + lane] + bias[lane];   // lane = expert id
    float myval = 0.f, m0 = 0.f;
    int myidx = 0;
#pragma unroll
    for (int k = 0; k < 8; ++k) {
      float bv = v;
      int   bi = lane;
#pragma unroll
      for (int off = 1; off < 64; off <<= 1) {    // argmax, min-index tiebreak
        const float ov = __shfl_xor(bv, off);
        const int   oi = __shfl_xor(bi, off);
        if (ov > bv || (ov == bv && oi < bi)) { bv = ov; bi = oi; }
      }
      if (k == 0) m0 = bv;
      if (lane == k) { myval = bv; myidx = bi; }
      if (lane == bi) v = -FLT_MAX;               // bi is wave-uniform
    }
    const float el = (lane < 8) ? expf(myval - m0) : 0.f;
    float ssum = el;
    ssum += __shfl_xor(ssum, 1);
    ssum += __shfl_xor(ssum, 2);
    ssum += __shfl_xor(ssum, 4);
    if (lane < 8) {
      const size_t tg = (size_t)g * 16 + tt;
      out[tg * 8 + lane] = el / ssum;                        // weights (f32)
      out[(size_t)TOKS * 8 + tg * 8 + lane] = (float)myidx;  // indices as f32
    }
  }
}

extern "C" void kernel_launch(void* const* d_in, const int* in_sizes, int n_in,
                              void* d_out, int out_size, void* d_ws, size_t ws_size,
                              hipStream_t stream) {
  const float* x    = (const float*)d_in[0];
  const float* wgt  = (const float*)d_in[1];
  const float* bias = (const float*)d_in[2];
  float* out  = (float*)d_out;
  float* part = (float*)d_ws;

  const size_t planeB = (size_t)NTILE * 4096 * sizeof(float);   // 4 MiB per K-slice
  const size_t wB     = (size_t)3 * WPE * sizeof(unsigned short); // 1.5 MiB
  int ks = 1;
  if (ws_size >= 4 * planeB + wB)      ks = 4;
  else if (ws_size >= 2 * planeB + wB) ks = 2;
  unsigned short* wsp = (unsigned short*)((char*)d_ws + (size_t)ks * planeB);

  hipLaunchKernelGGL(wsplit_kernel, dim3(NEXP * HDIM / (256 * 8)), dim3(256), 0, stream,
                     wgt, wsp);
  hipLaunchKernelGGL(router_mfma_kernel, dim3(NTILE, ks), dim3(256), 0, stream,
                     x, wsp, part, ks);
  hipLaunchKernelGGL(reduce_topk_kernel, dim3(TOKS / 16), dim3(64), 0, stream,
                     part, bias, out, ks);
}

// Round 11
// 237.067 us; speedup vs baseline: 1.1165x; 1.1165x over previous
//
#include <hip/hip_runtime.h>
#include <float.h>
#include <math.h>

#define TOKS 16384
#define HDIM 4096
#define NEXP 64
#define BM   64            // tokens per block tile
#define NTILE (TOKS / BM)  // 256
#define KS   8             // K-slices (split-K)
#define WPE  262144        // u16 elems per w bf16 plane (64*4096)

typedef __attribute__((ext_vector_type(8)))  short short8v;  // 8 bf16 = one A/B frag
typedef __attribute__((ext_vector_type(16))) float f32x16;   // C/D frag

// Exact 3-way bf16 split by truncation: v = s1+s2+s3+eps, eps <= 2^-24*|v|.
__device__ __forceinline__ void split3(float v, unsigned& b1, unsigned& b2, unsigned& b3) {
  unsigned xb = __float_as_uint(v);
  b1 = xb >> 16;
  float r = v - __uint_as_float(xb & 0xFFFF0000u);
  unsigned rb = __float_as_uint(r);
  b2 = rb >> 16;
  float r2 = r - __uint_as_float(rb & 0xFFFF0000u);
  b3 = __float_as_uint(r2) >> 16;
}
__device__ __forceinline__ void cvt2(float a, float b, unsigned& o1, unsigned& o2, unsigned& o3) {
  unsigned a1, a2, a3, c1, c2, c3;
  split3(a, a1, a2, a3);
  split3(b, c1, c2, c3);
  o1 = a1 | (c1 << 16); o2 = a2 | (c2 << 16); o3 = a3 | (c3 << 16);
}

// ---- pre-kernel: w [64][4096] f32 -> 3 bf16 planes [3][64][4096] (row-major) ----
__global__ __launch_bounds__(256)
void wsplit_kernel(const float* __restrict__ wgt, unsigned short* __restrict__ wsp) {
  const int gid  = blockIdx.x * 256 + threadIdx.x;   // 32768 threads x 8 elems
  const int base = gid * 8;
  const float4 f0 = *(const float4*)(wgt + base);
  const float4 f1 = *(const float4*)(wgt + base + 4);
  uint4 q1, q2, q3;
  cvt2(f0.x, f0.y, q1.x, q2.x, q3.x);
  cvt2(f0.z, f0.w, q1.y, q2.y, q3.y);
  cvt2(f1.x, f1.y, q1.z, q2.z, q3.z);
  cvt2(f1.z, f1.w, q1.w, q2.w, q3.w);
  *(uint4*)(wsp + base)            = q1;
  *(uint4*)(wsp + WPE + base)      = q2;
  *(uint4*)(wsp + 2 * WPE + base)  = q3;
}

// ---- stage 1: LDS-free register-streaming MFMA, explicit SW pipeline ----
// grid (256 tiles, KS). Block 256 thr = 4 waves (wm tok-half, we exp-half);
// wave = 32tok x 32exp via mfma_f32_32x32x16_bf16, frags read straight from
// global (A: fp32 x rows split in-reg; B: pre-split bf16 planes, L2-resident).
// R10 post-mortem: rolled loop = <=1 iter load-ahead -> 900cy HBM latency
// exposed (all counters idle). Fix: named A/B register pipeline, preload 2
// iterations, peeled tail; KS=8 -> 8 blocks/CU of TLP on top.
__global__ __launch_bounds__(256)
void router_mfma_kernel(const float* __restrict__ x,
                        const unsigned short* __restrict__ wsp,
                        float* __restrict__ part) {
  const int tid  = threadIdx.x;
  const int lane = tid & 63;
  const int wv   = tid >> 6;
  const int kt   = blockIdx.y;
  const int tokBase = blockIdx.x * BM;

  const int wm = wv >> 1, we = wv & 1;
  const int r  = lane & 31, h2 = lane >> 5;

  const int kSlice = HDIM / KS;        // 512
  const int kStart = kt * kSlice;
  const int NIT    = kSlice / 32;      // 16 iterations, 2 k16-steps each

  const float*          xp = x   + (size_t)(tokBase + wm * 32 + r) * HDIM + kStart + h2 * 8;
  const unsigned short* bp = wsp + (size_t)(we * 32 + r) * HDIM + kStart + h2 * 8;

  f32x16 acc_m0, acc_m1, acc_c;
#pragma unroll
  for (int i = 0; i < 16; ++i) { acc_m0[i] = 0.f; acc_m1[i] = 0.f; acc_c[i] = 0.f; }

  // pipeline buffers: iteration = 32 floats = 2 k16-steps
  float4  xa0_A, xb0_A, xa1_A, xb1_A, xa0_B, xb0_B, xa1_B, xb1_B;
  short8v b10_A, b20_A, b30_A, b11_A, b21_A, b31_A;
  short8v b10_B, b20_B, b30_B, b11_B, b21_B, b31_B;

#define LOADIT(S, it) do { \
    const float* xq_ = xp + (it) * 32; \
    xa0_##S = *(const float4*)(xq_);       xb0_##S = *(const float4*)(xq_ + 4); \
    xa1_##S = *(const float4*)(xq_ + 16);  xb1_##S = *(const float4*)(xq_ + 20); \
    const unsigned short* bq_ = bp + (it) * 32; \
    b10_##S = *(const short8v*)(bq_); \
    b20_##S = *(const short8v*)(bq_ + WPE); \
    b30_##S = *(const short8v*)(bq_ + 2 * WPE); \
    b11_##S = *(const short8v*)(bq_ + 16); \
    b21_##S = *(const short8v*)(bq_ + WPE + 16); \
    b31_##S = *(const short8v*)(bq_ + 2 * WPE + 16); \
  } while (0)

#define MFMA(a, b, c) __builtin_amdgcn_mfma_f32_32x32x16_bf16((a), (b), (c), 0, 0, 0)

#define HSTEP(xa, xb, w1, w2, w3, macc) do { \
    uint4 q1_, q2_, q3_; \
    cvt2((xa).x, (xa).y, q1_.x, q2_.x, q3_.x); \
    cvt2((xa).z, (xa).w, q1_.y, q2_.y, q3_.y); \
    cvt2((xb).x, (xb).y, q1_.z, q2_.z, q3_.z); \
    cvt2((xb).z, (xb).w, q1_.w, q2_.w, q3_.w); \
    const short8v a1_ = __builtin_bit_cast(short8v, q1_); \
    const short8v a2_ = __builtin_bit_cast(short8v, q2_); \
    const short8v a3_ = __builtin_bit_cast(short8v, q3_); \
    macc  = MFMA(a1_, (w1), macc); \
    acc_c = MFMA(a1_, (w2), acc_c); \
    acc_c = MFMA(a2_, (w1), acc_c); \
    acc_c = MFMA(a1_, (w3), acc_c); \
    acc_c = MFMA(a2_, (w2), acc_c); \
    acc_c = MFMA(a3_, (w1), acc_c); \
  } while (0)

#define COMPIT(S) do { \
    HSTEP(xa0_##S, xb0_##S, b10_##S, b20_##S, b30_##S, acc_m0); \
    HSTEP(xa1_##S, xb1_##S, b11_##S, b21_##S, b31_##S, acc_m1); \
  } while (0)

  // ---- pipeline: preload 2 iters; steady state keeps 2 in flight ----
  LOADIT(A, 0);
  LOADIT(B, 1);
#pragma unroll 1
  for (int it = 0; it + 3 < NIT; it += 2) {
    COMPIT(A);
    LOADIT(A, it + 2);
    COMPIT(B);
    LOADIT(B, it + 3);
  }
  COMPIT(A);   // NIT-2
  COMPIT(B);   // NIT-1

  // partial logits [kt][tile][64 tok][64 exp] (C/D: row=(reg&3)+8*(reg>>2)+4*h2)
  float* pp = part + ((size_t)kt * NTILE + blockIdx.x) * 4096;
#pragma unroll
  for (int reg = 0; reg < 16; ++reg) {
    const int rowf = (reg & 3) + 8 * (reg >> 2) + 4 * h2;
    pp[(wm * 32 + rowf) * 64 + we * 32 + r] = (acc_m0[reg] + acc_m1[reg]) + acc_c[reg];
  }
}

// ---- stage 2: sum KS partials + bias, top-8 + softmax. 1024 blocks x 64 thr ----
__global__ __launch_bounds__(64)
void reduce_topk_kernel(const float* __restrict__ part,
                        const float* __restrict__ bias,
                        float* __restrict__ out) {
  __shared__ __align__(16) float fin[1024];       // 16 tokens x 64 experts
  const int lane = threadIdx.x;                   // 0..63
  const int g    = blockIdx.x;                    // tokens 16g..16g+15
  const int tile = g >> 2;
  const int rowBase = (g & 3) * 16;

  const int row = lane >> 2;
  const int e0  = (lane & 3) * 16;
  const size_t off0 = (size_t)tile * 4096 + (rowBase + row) * 64 + e0;
  float4 s0 = make_float4(0.f, 0.f, 0.f, 0.f), s1 = s0, s2 = s0, s3 = s0;
#pragma unroll
  for (int kt = 0; kt < KS; ++kt) {
    const float* p = part + (size_t)kt * (NTILE * 4096) + off0;
    const float4 q0 = *(const float4*)(p);
    const float4 q1 = *(const float4*)(p + 4);
    const float4 q2 = *(const float4*)(p + 8);
    const float4 q3 = *(const float4*)(p + 12);
    s0.x += q0.x; s0.y += q0.y; s0.z += q0.z; s0.w += q0.w;
    s1.x += q1.x; s1.y += q1.y; s1.z += q1.z; s1.w += q1.w;
    s2.x += q2.x; s2.y += q2.y; s2.z += q2.z; s2.w += q2.w;
    s3.x += q3.x; s3.y += q3.y; s3.z += q3.z; s3.w += q3.w;
  }
  *(float4*)(&fin[lane * 16])      = s0;
  *(float4*)(&fin[lane * 16 + 4])  = s1;
  *(float4*)(&fin[lane * 16 + 8])  = s2;
  *(float4*)(&fin[lane * 16 + 12]) = s3;
  __syncthreads();

  for (int tt = 0; tt < 16; ++tt) {
    float v = fin[tt * 64 + lane] + bias[lane];   // lane = expert id
    float myval = 0.f, m0 = 0.f;
    int myidx = 0;
#pragma unroll
    for (int k = 0; k < 8; ++k) {
      float bv = v;
      int   bi = lane;
#pragma unroll
      for (int off = 1; off < 64; off <<= 1) {    // argmax, min-index tiebreak
        const float ov = __shfl_xor(bv, off);
        const int   oi = __shfl_xor(bi, off);
        if (ov > bv || (ov == bv && oi < bi)) { bv = ov; bi = oi; }
      }
      if (k == 0) m0 = bv;
      if (lane == k) { myval = bv; myidx = bi; }
      if (lane == bi) v = -FLT_MAX;               // bi is wave-uniform
    }
    const float el = (lane < 8) ? expf(myval - m0) : 0.f;
    float ssum = el;
    ssum += __shfl_xor(ssum, 1);
    ssum += __shfl_xor(ssum, 2);
    ssum += __shfl_xor(ssum, 4);
    if (lane < 8) {
      const size_t tg = (size_t)g * 16 + tt;
      out[tg * 8 + lane] = el / ssum;                        // weights (f32)
      out[(size_t)TOKS * 8 + tg * 8 + lane] = (float)myidx;  // indices as f32
    }
  }
}

extern "C" void kernel_launch(void* const* d_in, const int* in_sizes, int n_in,
                              void* d_out, int out_size, void* d_ws, size_t ws_size,
                              hipStream_t stream) {
  const float* x    = (const float*)d_in[0];
  const float* wgt  = (const float*)d_in[1];
  const float* bias = (const float*)d_in[2];
  float* out  = (float*)d_out;
  float* part = (float*)d_ws;   // KS planes of 4 MiB + 1.5 MiB w-planes (ws ~1 GB)

  unsigned short* wsp = (unsigned short*)((char*)d_ws + (size_t)KS * NTILE * 4096 * sizeof(float));

  hipLaunchKernelGGL(wsplit_kernel, dim3(NEXP * HDIM / (256 * 8)), dim3(256), 0, stream,
                     wgt, wsp);
  hipLaunchKernelGGL(router_mfma_kernel, dim3(NTILE, KS), dim3(256), 0, stream,
                     x, wsp, part);
  hipLaunchKernelGGL(reduce_topk_kernel, dim3(TOKS / 16), dim3(64), 0, stream,
                     part, bias, out);
}

// Round 12
// 231.401 us; speedup vs baseline: 1.1438x; 1.0245x over previous
//
#include <hip/hip_runtime.h>
#include <float.h>
#include <math.h>

#define TOKS 16384
#define HDIM 4096
#define NEXP 64
#define BM   64            // tokens per block tile
#define NTILE (TOKS / BM)  // 256
#define KS   4             // K-slices; kSlice = 1024 = 16 chunks of BK=64
#define NCHS 16            // chunks per slice
#define WPE  262144        // u16 elems per w bf16 plane (64*4096)

typedef __attribute__((ext_vector_type(8)))  short short8v;  // 8 bf16 = one A/B frag
typedef __attribute__((ext_vector_type(16))) float f32x16;   // C/D frag

// Exact 3-way bf16 split by truncation: v = s1+s2+s3+eps, eps <= 2^-24*|v|.
__device__ __forceinline__ void split3(float v, unsigned& b1, unsigned& b2, unsigned& b3) {
  unsigned xb = __float_as_uint(v);
  b1 = xb >> 16;
  float r = v - __uint_as_float(xb & 0xFFFF0000u);
  unsigned rb = __float_as_uint(r);
  b2 = rb >> 16;
  float r2 = r - __uint_as_float(rb & 0xFFFF0000u);
  b3 = __float_as_uint(r2) >> 16;
}
__device__ __forceinline__ void cvt2(float a, float b, unsigned& o1, unsigned& o2, unsigned& o3) {
  unsigned a1, a2, a3, c1, c2, c3;
  split3(a, a1, a2, a3);
  split3(b, c1, c2, c3);
  o1 = a1 | (c1 << 16); o2 = a2 | (c2 << 16); o3 = a3 | (c3 << 16);
}

// ---- pre-kernel: w [64][4096] f32 -> 3 bf16 planes [3][64][4096] (row-major) ----
__global__ __launch_bounds__(256)
void wsplit_kernel(const float* __restrict__ wgt, unsigned short* __restrict__ wsp) {
  const int gid  = blockIdx.x * 256 + threadIdx.x;   // 32768 threads x 8 elems
  const int base = gid * 8;
  const float4 f0 = *(const float4*)(wgt + base);
  const float4 f1 = *(const float4*)(wgt + base + 4);
  uint4 q1, q2, q3;
  cvt2(f0.x, f0.y, q1.x, q2.x, q3.x);
  cvt2(f0.z, f0.w, q1.y, q2.y, q3.y);
  cvt2(f1.x, f1.y, q1.z, q2.z, q3.z);
  cvt2(f1.z, f1.w, q1.w, q2.w, q3.w);
  *(uint4*)(wsp + base)            = q1;
  *(uint4*)(wsp + WPE + base)      = q2;
  *(uint4*)(wsp + 2 * WPE + base)  = q3;
}

// ---- stage 1: hybrid. x: coalesced GLOAD -> split -> LDS (dbuf, 1 bar/chunk);
//      w: B-frags direct from pre-split bf16 planes (L2/L3-resident). ----
// grid (256 tiles, KS). Block 256 thr = 4 waves (wm tok-half, we exp-half);
// wave = 32tok x 32exp, mfma_f32_32x32x16_bf16, 6 MFMA per k16 (3-way split).
// LDS: 2 buf x 3 planes x [64 rows][64 k] bf16 = 48 KB -> 3 blocks/CU.
__global__ __launch_bounds__(256)
void router_mfma_kernel(const float* __restrict__ x,
                        const unsigned short* __restrict__ wsp,
                        float* __restrict__ part) {
  __shared__ __align__(16) unsigned char smem[49152];
  const int tid  = threadIdx.x;
  const int lane = tid & 63;
  const int wv   = tid >> 6;
  const int kt   = blockIdx.y;
  const int tokBase = blockIdx.x * BM;
  const int kStart  = kt * (HDIM / KS);

  // staging: thread owns x row stok, k-seg of 16 floats
  const int stok = tid >> 2;
  const int seg  = tid & 3;
  const unsigned swz0 = (unsigned)(((seg * 2)     ^ (stok & 7)) << 4);
  const unsigned swz1 = (unsigned)(((seg * 2 + 1) ^ (stok & 7)) << 4);
  const int rowbyte_s = stok * 128;
  const float* const xrow = x + (size_t)(tokBase + stok) * HDIM + kStart;

  // compute mapping
  const int wm = wv >> 1, we = wv & 1;
  const int r  = lane & 31, h2 = lane >> 5;
  const int r7 = r & 7;
  const int byteA = (wm * 32 + r) * 128;
  const unsigned short* const bp = wsp + (size_t)(we * 32 + r) * HDIM + kStart + h2 * 8;

  f32x16 acc_m0, acc_m1, acc_c;
#pragma unroll
  for (int i = 0; i < 16; ++i) { acc_m0[i] = 0.f; acc_m1[i] = 0.f; acc_c[i] = 0.f; }

  float4 nf0, nf1, nf2, nf3;   // staged x chunk (16 f32)

#define GLOAD(c) do { \
    const float* p_ = xrow + (c) * 64 + seg * 16; \
    nf0 = *(const float4*)(p_);      nf1 = *(const float4*)(p_ + 4); \
    nf2 = *(const float4*)(p_ + 8);  nf3 = *(const float4*)(p_ + 12); \
  } while (0)

  // split x -> 3 bf16 planes in LDS (granule-XOR swizzle), 6 ds_write_b128
#define SWRITE(b) do { \
    unsigned char* bb_ = smem + (b) * 24576; \
    uint4 q1l, q2l, q3l, q1h, q2h, q3h; \
    cvt2(nf0.x, nf0.y, q1l.x, q2l.x, q3l.x); \
    cvt2(nf0.z, nf0.w, q1l.y, q2l.y, q3l.y); \
    cvt2(nf1.x, nf1.y, q1l.z, q2l.z, q3l.z); \
    cvt2(nf1.z, nf1.w, q1l.w, q2l.w, q3l.w); \
    cvt2(nf2.x, nf2.y, q1h.x, q2h.x, q3h.x); \
    cvt2(nf2.z, nf2.w, q1h.y, q2h.y, q3h.y); \
    cvt2(nf3.x, nf3.y, q1h.z, q2h.z, q3h.z); \
    cvt2(nf3.z, nf3.w, q1h.w, q2h.w, q3h.w); \
    *(uint4*)(bb_ +     0 + rowbyte_s + swz0) = q1l; \
    *(uint4*)(bb_ +     0 + rowbyte_s + swz1) = q1h; \
    *(uint4*)(bb_ +  8192 + rowbyte_s + swz0) = q2l; \
    *(uint4*)(bb_ +  8192 + rowbyte_s + swz1) = q2h; \
    *(uint4*)(bb_ + 16384 + rowbyte_s + swz0) = q3l; \
    *(uint4*)(bb_ + 16384 + rowbyte_s + swz1) = q3h; \
  } while (0)

#define MFMA(a, b, c) __builtin_amdgcn_mfma_f32_32x32x16_bf16((a), (b), (c), 0, 0, 0)

  // one chunk: 4 k16-steps; A from LDS (swizzled), B direct from global planes
#define COMPUTE(b, c) do { \
    const unsigned char* bb_ = smem + (b) * 24576; \
    _Pragma("unroll") \
    for (int s = 0; s < 4; ++s) { \
      const int off_ = ((2 * s + h2) ^ r7) << 4; \
      const short8v a1_ = *(const short8v*)(bb_ +     0 + byteA + off_); \
      const short8v a2_ = *(const short8v*)(bb_ +  8192 + byteA + off_); \
      const short8v a3_ = *(const short8v*)(bb_ + 16384 + byteA + off_); \
      const unsigned short* bq_ = bp + (c) * 64 + s * 16; \
      const short8v b1_ = *(const short8v*)(bq_); \
      const short8v b2_ = *(const short8v*)(bq_ + WPE); \
      const short8v b3_ = *(const short8v*)(bq_ + 2 * WPE); \
      if (s < 2) acc_m0 = MFMA(a1_, b1_, acc_m0); \
      else       acc_m1 = MFMA(a1_, b1_, acc_m1); \
      acc_c = MFMA(a1_, b2_, acc_c); \
      acc_c = MFMA(a2_, b1_, acc_c); \
      acc_c = MFMA(a1_, b3_, acc_c); \
      acc_c = MFMA(a2_, b2_, acc_c); \
      acc_c = MFMA(a3_, b1_, acc_c); \
      __builtin_amdgcn_sched_barrier(0); \
    } \
  } while (0)

  // ---- dbuf, ONE barrier per chunk ----
  // iter c: SWRITE(buf^1, chunk c+1 regs); GLOAD(c+2); COMPUTE(buf, c); bar.
  GLOAD(0);
  SWRITE(0);        // chunk 0 -> buf 0
  GLOAD(1);
  __syncthreads();
  int buf = 0;
#pragma unroll 1
  for (int c = 0; c < NCHS; ++c) {
    if (c + 1 < NCHS) {
      SWRITE(buf ^ 1);                 // chunk c+1 regs -> other buffer
      if (c + 2 < NCHS) GLOAD(c + 2);  // prefetch chunk c+2
    }
    COMPUTE(buf, c);
    __syncthreads();
    buf ^= 1;
  }

  // partial logits [kt][tile][64 tok][64 exp] (C/D: row=(reg&3)+8*(reg>>2)+4*h2)
  float* pp = part + ((size_t)kt * NTILE + blockIdx.x) * 4096;
#pragma unroll
  for (int reg = 0; reg < 16; ++reg) {
    const int rowf = (reg & 3) + 8 * (reg >> 2) + 4 * h2;
    pp[(wm * 32 + rowf) * 64 + we * 32 + r] = (acc_m0[reg] + acc_m1[reg]) + acc_c[reg];
  }
}

// ---- stage 2: sum KS partials + bias, top-8 + softmax. 1024 blocks x 64 thr ----
__global__ __launch_bounds__(64)
void reduce_topk_kernel(const float* __restrict__ part,
                        const float* __restrict__ bias,
                        float* __restrict__ out) {
  __shared__ __align__(16) float fin[1024];       // 16 tokens x 64 experts
  const int lane = threadIdx.x;                   // 0..63
  const int g    = blockIdx.x;                    // tokens 16g..16g+15
  const int tile = g >> 2;
  const int rowBase = (g & 3) * 16;

  const int row = lane >> 2;
  const int e0  = (lane & 3) * 16;
  const size_t off0 = (size_t)tile * 4096 + (rowBase + row) * 64 + e0;
  float4 s0 = make_float4(0.f, 0.f, 0.f, 0.f), s1 = s0, s2 = s0, s3 = s0;
#pragma unroll
  for (int kt = 0; kt < KS; ++kt) {
    const float* p = part + (size_t)kt * (NTILE * 4096) + off0;
    const float4 q0 = *(const float4*)(p);
    const float4 q1 = *(const float4*)(p + 4);
    const float4 q2 = *(const float4*)(p + 8);
    const float4 q3 = *(const float4*)(p + 12);
    s0.x += q0.x; s0.y += q0.y; s0.z += q0.z; s0.w += q0.w;
    s1.x += q1.x; s1.y += q1.y; s1.z += q1.z; s1.w += q1.w;
    s2.x += q2.x; s2.y += q2.y; s2.z += q2.z; s2.w += q2.w;
    s3.x += q3.x; s3.y += q3.y; s3.z += q3.z; s3.w += q3.w;
  }
  *(float4*)(&fin[lane * 16])      = s0;
  *(float4*)(&fin[lane * 16 + 4])  = s1;
  *(float4*)(&fin[lane * 16 + 8])  = s2;
  *(float4*)(&fin[lane * 16 + 12]) = s3;
  __syncthreads();

  for (int tt = 0; tt < 16; ++tt) {
    float v = fin[tt * 64 + lane] + bias[lane];   // lane = expert id
    float myval = 0.f, m0 = 0.f;
    int myidx = 0;
#pragma unroll
    for (int k = 0; k < 8; ++k) {
      float bv = v;
      int   bi = lane;
#pragma unroll
      for (int off = 1; off < 64; off <<= 1) {    // argmax, min-index tiebreak
        const float ov = __shfl_xor(bv, off);
        const int   oi = __shfl_xor(bi, off);
        if (ov > bv || (ov == bv && oi < bi)) { bv = ov; bi = oi; }
      }
      if (k == 0) m0 = bv;
      if (lane == k) { myval = bv; myidx = bi; }
      if (lane == bi) v = -FLT_MAX;               // bi is wave-uniform
    }
    const float el = (lane < 8) ? expf(myval - m0) : 0.f;
    float ssum = el;
    ssum += __shfl_xor(ssum, 1);
    ssum += __shfl_xor(ssum, 2);
    ssum += __shfl_xor(ssum, 4);
    if (lane < 8) {
      const size_t tg = (size_t)g * 16 + tt;
      out[tg * 8 + lane] = el / ssum;                        // weights (f32)
      out[(size_t)TOKS * 8 + tg * 8 + lane] = (float)myidx;  // indices as f32
    }
  }
}

extern "C" void kernel_launch(void* const* d_in, const int* in_sizes, int n_in,
                              void* d_out, int out_size, void* d_ws, size_t ws_size,
                              hipStream_t stream) {
  const float* x    = (const float*)d_in[0];
  const float* wgt  = (const float*)d_in[1];
  const float* bias = (const float*)d_in[2];
  float* out  = (float*)d_out;
  float* part = (float*)d_ws;   // KS planes x 4 MiB, then 1.5 MiB w-planes

  unsigned short* wsp = (unsigned short*)((char*)d_ws + (size_t)KS * NTILE * 4096 * sizeof(float));

  hipLaunchKernelGGL(wsplit_kernel, dim3(NEXP * HDIM / (256 * 8)), dim3(256), 0, stream,
                     wgt, wsp);
  hipLaunchKernelGGL(router_mfma_kernel, dim3(NTILE, KS), dim3(256), 0, stream,
                     x, wsp, part);
  hipLaunchKernelGGL(reduce_topk_kernel, dim3(TOKS / 16), dim3(64), 0, stream,
                     part, bias, out);
}

// Round 13
// 217.225 us; speedup vs baseline: 1.2185x; 1.0653x over previous
//
#include <hip/hip_runtime.h>
#include <float.h>
#include <math.h>

#define TOKS 16384
#define HDIM 4096
#define NEXP 64
#define BM   64            // tokens per block tile
#define NTILE (TOKS / BM)  // 256
#define KS   8             // K-slices; kSlice = 512 = 8 chunks of BK=64
#define NCHS 8             // chunks per slice
#define WPE  262144        // u16 elems per w bf16 plane (64*4096)

typedef __attribute__((ext_vector_type(8)))  short short8v;  // 8 bf16 = one A/B frag
typedef __attribute__((ext_vector_type(16))) float f32x16;   // C/D frag

// Exact 3-way bf16 split by truncation: v = s1+s2+s3+eps, eps <= 2^-24*|v|.
__device__ __forceinline__ void split3(float v, unsigned& b1, unsigned& b2, unsigned& b3) {
  unsigned xb = __float_as_uint(v);
  b1 = xb >> 16;
  float r = v - __uint_as_float(xb & 0xFFFF0000u);
  unsigned rb = __float_as_uint(r);
  b2 = rb >> 16;
  float r2 = r - __uint_as_float(rb & 0xFFFF0000u);
  b3 = __float_as_uint(r2) >> 16;
}
__device__ __forceinline__ void cvt2(float a, float b, unsigned& o1, unsigned& o2, unsigned& o3) {
  unsigned a1, a2, a3, c1, c2, c3;
  split3(a, a1, a2, a3);
  split3(b, c1, c2, c3);
  o1 = a1 | (c1 << 16); o2 = a2 | (c2 << 16); o3 = a3 | (c3 << 16);
}

// ---- pre-kernel: w [64][4096] f32 -> 3 bf16 planes [3][64][4096] (row-major) ----
__global__ __launch_bounds__(256)
void wsplit_kernel(const float* __restrict__ wgt, unsigned short* __restrict__ wsp) {
  const int gid  = blockIdx.x * 256 + threadIdx.x;   // 32768 threads x 8 elems
  const int base = gid * 8;
  const float4 f0 = *(const float4*)(wgt + base);
  const float4 f1 = *(const float4*)(wgt + base + 4);
  uint4 q1, q2, q3;
  cvt2(f0.x, f0.y, q1.x, q2.x, q3.x);
  cvt2(f0.z, f0.w, q1.y, q2.y, q3.y);
  cvt2(f1.x, f1.y, q1.z, q2.z, q3.z);
  cvt2(f1.z, f1.w, q1.w, q2.w, q3.w);
  *(uint4*)(wsp + base)            = q1;
  *(uint4*)(wsp + WPE + base)      = q2;
  *(uint4*)(wsp + 2 * WPE + base)  = q3;
}

__device__ __forceinline__ void gload_lds16(const float* g, void* l) {
  __builtin_amdgcn_global_load_lds((const __attribute__((address_space(1))) void*)g,
                                   (__attribute__((address_space(3))) void*)l, 16, 0, 0);
}

// ---- stage 1 ----
// grid (256 tiles, KS=8). Block 256 thr = 4 waves (wm tok-half, we exp-half);
// wave = 32tok x 32exp, mfma_f32_32x32x16_bf16, 6 MFMA/k16 via 3-way split.
// x: global_load_lds DMA of raw fp32 chunk [64 tok][64 k] with PRE-SWIZZLED
//    source granules (g -> g ^ ((g>>4)&7), involution; rule #21) into a linear
//    LDS dest; split to bf16 at LDS-read time.
// w: B-frags direct from pre-split bf16 planes (1.5 MB, L2-resident).
// 5 accumulator chains (m0,m1,c0,c1,c2) break the R8-R12 dependent-MFMA
// serialization; no sched_barrier -> B-loads hoist freely.
// LDS 2 x 16 KB = 32 KB -> ~5 blocks/CU of barrier-phase-staggered TLP.
__global__ __launch_bounds__(256)
void router_mfma_kernel(const float* __restrict__ x,
                        const unsigned short* __restrict__ wsp,
                        float* __restrict__ part) {
  __shared__ __align__(16) unsigned char smem[32768];
  const int tid  = threadIdx.x;
  const int lane = tid & 63;
  const int wv   = tid >> 6;
  const int kt   = blockIdx.y;
  const int tokBase = blockIdx.x * BM;
  const int kStart  = kt * (HDIM / KS);

  // staging source granules (4 per thread): lds granule G = j*256+tid,
  // global granule g = G ^ ((G>>4)&7); tok = g>>4, 16B-seg = g&15.
  const float* xg[4];
#pragma unroll
  for (int j = 0; j < 4; ++j) {
    const unsigned G = j * 256 + tid;
    const unsigned g = G ^ ((G >> 4) & 7);
    xg[j] = x + (size_t)(tokBase + (g >> 4)) * HDIM + kStart + (g & 15) * 4;
  }
  // wave-uniform LDS dest bases (lane*16 implicit in the DMA)
  const int ldsb = (wv * 1024) + ((tid & 63) ? 0 : 0);  // wv*1024 within each 4KB j-plane

  // compute mapping
  const int wm = wv >> 1, we = wv & 1;
  const int r  = lane & 31, h2 = lane >> 5;
  const int rowA = wm * 32 + r;
  const int r7A  = rowA & 7;
  const unsigned short* const bp = wsp + (size_t)(we * 32 + r) * HDIM + kStart + h2 * 8;

  f32x16 m0, m1, c0, c1, c2;
#pragma unroll
  for (int i = 0; i < 16; ++i) { m0[i] = 0.f; m1[i] = 0.f; c0[i] = 0.f; c1[i] = 0.f; c2[i] = 0.f; }

#define STAGE(buf, c) do { \
    unsigned char* lb_ = smem + (buf) * 16384; \
    gload_lds16(xg[0] + (c) * 64, lb_ +     0 + ldsb); \
    gload_lds16(xg[1] + (c) * 64, lb_ +  4096 + ldsb); \
    gload_lds16(xg[2] + (c) * 64, lb_ +  8192 + ldsb); \
    gload_lds16(xg[3] + (c) * 64, lb_ + 12288 + ldsb); \
  } while (0)

#define MFMA(a, b, c) __builtin_amdgcn_mfma_f32_32x32x16_bf16((a), (b), (c), 0, 0, 0)

#define COMPUTE(buf, c) do { \
    const unsigned char* bb_ = smem + (buf) * 16384; \
    _Pragma("unroll") \
    for (int s = 0; s < 4; ++s) { \
      const unsigned g0_ = rowA * 16 + s * 4 + h2 * 2; \
      const float4 xlo_ = *(const float4*)(bb_ + ((g0_ ^ r7A) << 4)); \
      const float4 xhi_ = *(const float4*)(bb_ + (((g0_ + 1) ^ r7A) << 4)); \
      uint4 q1_, q2_, q3_; \
      cvt2(xlo_.x, xlo_.y, q1_.x, q2_.x, q3_.x); \
      cvt2(xlo_.z, xlo_.w, q1_.y, q2_.y, q3_.y); \
      cvt2(xhi_.x, xhi_.y, q1_.z, q2_.z, q3_.z); \
      cvt2(xhi_.z, xhi_.w, q1_.w, q2_.w, q3_.w); \
      const short8v a1_ = __builtin_bit_cast(short8v, q1_); \
      const short8v a2_ = __builtin_bit_cast(short8v, q2_); \
      const short8v a3_ = __builtin_bit_cast(short8v, q3_); \
      const unsigned short* bq_ = bp + (c) * 64 + s * 16; \
      const short8v b1_ = *(const short8v*)(bq_); \
      const short8v b2_ = *(const short8v*)(bq_ + WPE); \
      const short8v b3_ = *(const short8v*)(bq_ + 2 * WPE); \
      if (s < 2) m0 = MFMA(a1_, b1_, m0); \
      else       m1 = MFMA(a1_, b1_, m1); \
      c0 = MFMA(a1_, b2_, c0); \
      c1 = MFMA(a2_, b1_, c1); \
      c2 = MFMA(a1_, b3_, c2); \
      c0 = MFMA(a2_, b2_, c0); \
      c1 = MFMA(a3_, b1_, c1); \
    } \
  } while (0)

  // ---- dbuf, one barrier per chunk; stage c+1 DMA overlaps compute c ----
  STAGE(0, 0);
  __syncthreads();            // drains DMA -> chunk 0 ready
  int buf = 0;
#pragma unroll 1
  for (int c = 0; c < NCHS; ++c) {
    if (c + 1 < NCHS) STAGE(buf ^ 1, c + 1);
    COMPUTE(buf, c);
    __syncthreads();          // next chunk's DMA drained here
    buf ^= 1;
  }

  // partial logits [kt][tile][64 tok][64 exp] (C/D: row=(reg&3)+8*(reg>>2)+4*h2)
  float* pp = part + ((size_t)kt * NTILE + blockIdx.x) * 4096;
#pragma unroll
  for (int reg = 0; reg < 16; ++reg) {
    const int rowf = (reg & 3) + 8 * (reg >> 2) + 4 * h2;
    pp[(wm * 32 + rowf) * 64 + we * 32 + r] =
        ((m0[reg] + m1[reg]) + (c0[reg] + c1[reg])) + c2[reg];
  }
}

// ---- stage 2: sum KS partials + bias, top-8 + softmax. 1024 blocks x 64 thr ----
__global__ __launch_bounds__(64)
void reduce_topk_kernel(const float* __restrict__ part,
                        const float* __restrict__ bias,
                        float* __restrict__ out) {
  __shared__ __align__(16) float fin[1024];       // 16 tokens x 64 experts
  const int lane = threadIdx.x;                   // 0..63
  const int g    = blockIdx.x;                    // tokens 16g..16g+15
  const int tile = g >> 2;
  const int rowBase = (g & 3) * 16;

  const int row = lane >> 2;
  const int e0  = (lane & 3) * 16;
  const size_t off0 = (size_t)tile * 4096 + (rowBase + row) * 64 + e0;
  float4 s0 = make_float4(0.f, 0.f, 0.f, 0.f), s1 = s0, s2 = s0, s3 = s0;
#pragma unroll
  for (int kt = 0; kt < KS; ++kt) {
    const float* p = part + (size_t)kt * (NTILE * 4096) + off0;
    const float4 q0 = *(const float4*)(p);
    const float4 q1 = *(const float4*)(p + 4);
    const float4 q2 = *(const float4*)(p + 8);
    const float4 q3 = *(const float4*)(p + 12);
    s0.x += q0.x; s0.y += q0.y; s0.z += q0.z; s0.w += q0.w;
    s1.x += q1.x; s1.y += q1.y; s1.z += q1.z; s1.w += q1.w;
    s2.x += q2.x; s2.y += q2.y; s2.z += q2.z; s2.w += q2.w;
    s3.x += q3.x; s3.y += q3.y; s3.z += q3.z; s3.w += q3.w;
  }
  *(float4*)(&fin[lane * 16])      = s0;
  *(float4*)(&fin[lane * 16 + 4])  = s1;
  *(float4*)(&fin[lane * 16 + 8])  = s2;
  *(float4*)(&fin[lane * 16 + 12]) = s3;
  __syncthreads();

  for (int tt = 0; tt < 16; ++tt) {
    float v = fin[tt * 64 + lane] + bias[lane];   // lane = expert id
    float myval = 0.f, m0 = 0.f;
    int myidx = 0;
#pragma unroll
    for (int k = 0; k < 8; ++k) {
      float bv = v;
      int   bi = lane;
#pragma unroll
      for (int off = 1; off < 64; off <<= 1) {    // argmax, min-index tiebreak
        const float ov = __shfl_xor(bv, off);
        const int   oi = __shfl_xor(bi, off);
        if (ov > bv || (ov == bv && oi < bi)) { bv = ov; bi = oi; }
      }
      if (k == 0) m0 = bv;
      if (lane == k) { myval = bv; myidx = bi; }
      if (lane == bi) v = -FLT_MAX;               // bi is wave-uniform
    }
    const float el = (lane < 8) ? expf(myval - m0) : 0.f;
    float ssum = el;
    ssum += __shfl_xor(ssum, 1);
    ssum += __shfl_xor(ssum, 2);
    ssum += __shfl_xor(ssum, 4);
    if (lane < 8) {
      const size_t tg = (size_t)g * 16 + tt;
      out[tg * 8 + lane] = el / ssum;                        // weights (f32)
      out[(size_t)TOKS * 8 + tg * 8 + lane] = (float)myidx;  // indices as f32
    }
  }
}

extern "C" void kernel_launch(void* const* d_in, const int* in_sizes, int n_in,
                              void* d_out, int out_size, void* d_ws, size_t ws_size,
                              hipStream_t stream) {
  const float* x    = (const float*)d_in[0];
  const float* wgt  = (const float*)d_in[1];
  const float* bias = (const float*)d_in[2];
  float* out  = (float*)d_out;
  float* part = (float*)d_ws;   // KS planes x 4 MiB, then 1.5 MiB w-planes

  unsigned short* wsp = (unsigned short*)((char*)d_ws + (size_t)KS * NTILE * 4096 * sizeof(float));

  hipLaunchKernelGGL(wsplit_kernel, dim3(NEXP * HDIM / (256 * 8)), dim3(256), 0, stream,
                     wgt, wsp);
  hipLaunchKernelGGL(router_mfma_kernel, dim3(NTILE, KS), dim3(256), 0, stream,
                     x, wsp, part);
  hipLaunchKernelGGL(reduce_topk_kernel, dim3(TOKS / 16), dim3(64), 0, stream,
                     part, bias, out);
}

// Round 14
// 197.008 us; speedup vs baseline: 1.3435x; 1.1026x over previous
//
#include <hip/hip_runtime.h>
#include <float.h>
#include <math.h>

#define TOKS 16384
#define HDIM 4096
#define NEXP 64
#define BM   64            // tokens per block tile
#define NTILE (TOKS / BM)  // 256
#define KS   4             // K-slices; kSlice = 1024 = 16 chunks of BK=64
#define NCHS 16            // chunks per slice
#define WPE  262144        // u16 elems per w bf16 plane (64*4096)

typedef __attribute__((ext_vector_type(8)))  short short8v;  // 8 bf16 = one A/B frag
typedef __attribute__((ext_vector_type(16))) float f32x16;   // C/D frag

// Exact 3-way bf16 split by truncation: v = s1+s2+s3+eps, eps <= 2^-24*|v|.
__device__ __forceinline__ void split3(float v, unsigned& b1, unsigned& b2, unsigned& b3) {
  unsigned xb = __float_as_uint(v);
  b1 = xb >> 16;
  float r = v - __uint_as_float(xb & 0xFFFF0000u);
  unsigned rb = __float_as_uint(r);
  b2 = rb >> 16;
  float r2 = r - __uint_as_float(rb & 0xFFFF0000u);
  b3 = __float_as_uint(r2) >> 16;
}
__device__ __forceinline__ void cvt2(float a, float b, unsigned& o1, unsigned& o2, unsigned& o3) {
  unsigned a1, a2, a3, c1, c2, c3;
  split3(a, a1, a2, a3);
  split3(b, c1, c2, c3);
  o1 = a1 | (c1 << 16); o2 = a2 | (c2 << 16); o3 = a3 | (c3 << 16);
}

// ---- pre-kernel: w [64][4096] f32 -> 3 bf16 planes [3][64][4096] (row-major) ----
__global__ __launch_bounds__(256)
void wsplit_kernel(const float* __restrict__ wgt, unsigned short* __restrict__ wsp) {
  const int gid  = blockIdx.x * 256 + threadIdx.x;   // 32768 threads x 8 elems
  const int base = gid * 8;
  const float4 f0 = *(const float4*)(wgt + base);
  const float4 f1 = *(const float4*)(wgt + base + 4);
  uint4 q1, q2, q3;
  cvt2(f0.x, f0.y, q1.x, q2.x, q3.x);
  cvt2(f0.z, f0.w, q1.y, q2.y, q3.y);
  cvt2(f1.x, f1.y, q1.z, q2.z, q3.z);
  cvt2(f1.z, f1.w, q1.w, q2.w, q3.w);
  *(uint4*)(wsp + base)            = q1;
  *(uint4*)(wsp + WPE + base)      = q2;
  *(uint4*)(wsp + 2 * WPE + base)  = q3;
}

__device__ __forceinline__ void gload_lds16(const float* g, void* l) {
  __builtin_amdgcn_global_load_lds((const __attribute__((address_space(1))) void*)g,
                                   (__attribute__((address_space(3))) void*)l, 16, 0, 0);
}

#define WAITVM(N) do { asm volatile("s_waitcnt vmcnt(" #N ")" ::: "memory"); \
                       __builtin_amdgcn_sched_barrier(0); } while (0)
#define RBAR()    do { __builtin_amdgcn_s_barrier(); \
                       __builtin_amdgcn_sched_barrier(0); } while (0)

// ---- stage 1: R13 datapath + m201-style counted-vmcnt pipeline ----
// Triple-buffered LDS (3 x 16 KB). Raw s_barrier + per-wave counted vmcnt:
// each wave waits only for ITS chunk-c DMAs (vmcnt(8): 2 newer chunks stay in
// flight); barrier => union of all waves' quarters landed. The __syncthreads
// vmcnt(0) drain that froze R8-R13's pipeline at depth 0 is gone.
__global__ __launch_bounds__(256)
void router_mfma_kernel(const float* __restrict__ x,
                        const unsigned short* __restrict__ wsp,
                        float* __restrict__ part) {
  __shared__ __align__(16) unsigned char smem[49152];
  const int tid  = threadIdx.x;
  const int lane = tid & 63;
  const int wv   = tid >> 6;
  const int kt   = blockIdx.y;
  const int tokBase = blockIdx.x * BM;
  const int kStart  = kt * (HDIM / KS);

  // staging source granules (4 per thread): lds granule G = j*256+tid,
  // global granule g = G ^ ((G>>4)&7); tok = g>>4, 16B-seg = g&15. (R13, verified)
  const float* xg[4];
#pragma unroll
  for (int j = 0; j < 4; ++j) {
    const unsigned G = j * 256 + tid;
    const unsigned g = G ^ ((G >> 4) & 7);
    xg[j] = x + (size_t)(tokBase + (g >> 4)) * HDIM + kStart + (g & 15) * 4;
  }
  const int ldsb = wv * 1024;

  // compute mapping (R13, verified)
  const int wm = wv >> 1, we = wv & 1;
  const int r  = lane & 31, h2 = lane >> 5;
  const int rowA = wm * 32 + r;
  const int r7A  = rowA & 7;
  const unsigned short* const bp = wsp + (size_t)(we * 32 + r) * HDIM + kStart + h2 * 8;

  f32x16 m0, m1, c0, c1, c2;
#pragma unroll
  for (int i = 0; i < 16; ++i) { m0[i] = 0.f; m1[i] = 0.f; c0[i] = 0.f; c1[i] = 0.f; c2[i] = 0.f; }

#define STAGE(buf, c) do { \
    unsigned char* lb_ = smem + (buf) * 16384; \
    gload_lds16(xg[0] + (c) * 64, lb_ +     0 + ldsb); \
    gload_lds16(xg[1] + (c) * 64, lb_ +  4096 + ldsb); \
    gload_lds16(xg[2] + (c) * 64, lb_ +  8192 + ldsb); \
    gload_lds16(xg[3] + (c) * 64, lb_ + 12288 + ldsb); \
  } while (0)

#define MFMA(a, b, c) __builtin_amdgcn_mfma_f32_32x32x16_bf16((a), (b), (c), 0, 0, 0)

#define COMPUTE(buf, c) do { \
    const unsigned char* bb_ = smem + (buf) * 16384; \
    _Pragma("unroll") \
    for (int s = 0; s < 4; ++s) { \
      const unsigned g0_ = rowA * 16 + s * 4 + h2 * 2; \
      const float4 xlo_ = *(const float4*)(bb_ + ((g0_ ^ r7A) << 4)); \
      const float4 xhi_ = *(const float4*)(bb_ + (((g0_ + 1) ^ r7A) << 4)); \
      uint4 q1_, q2_, q3_; \
      cvt2(xlo_.x, xlo_.y, q1_.x, q2_.x, q3_.x); \
      cvt2(xlo_.z, xlo_.w, q1_.y, q2_.y, q3_.y); \
      cvt2(xhi_.x, xhi_.y, q1_.z, q2_.z, q3_.z); \
      cvt2(xhi_.z, xhi_.w, q1_.w, q2_.w, q3_.w); \
      const short8v a1_ = __builtin_bit_cast(short8v, q1_); \
      const short8v a2_ = __builtin_bit_cast(short8v, q2_); \
      const short8v a3_ = __builtin_bit_cast(short8v, q3_); \
      const unsigned short* bq_ = bp + (c) * 64 + s * 16; \
      const short8v b1_ = *(const short8v*)(bq_); \
      const short8v b2_ = *(const short8v*)(bq_ + WPE); \
      const short8v b3_ = *(const short8v*)(bq_ + 2 * WPE); \
      if (s < 2) m0 = MFMA(a1_, b1_, m0); \
      else       m1 = MFMA(a1_, b1_, m1); \
      c0 = MFMA(a1_, b2_, c0); \
      c1 = MFMA(a2_, b1_, c1); \
      c2 = MFMA(a1_, b3_, c2); \
      c0 = MFMA(a2_, b2_, c0); \
      c1 = MFMA(a3_, b1_, c1); \
    } \
  } while (0)

  // ---- prologue: fill 3 buffers; wait only for chunk 0 (8 newer stay in flight)
  STAGE(0, 0);
  STAGE(1, 1);
  STAGE(2, 2);
  WAITVM(8);
  RBAR();

#pragma unroll 1
  for (int c = 0; c < NCHS; ++c) {
    COMPUTE(c % 3, c);
    RBAR();                              // all waves done READING buf c%3
    if (c + 3 < NCHS) STAGE(c % 3, c + 3);
    if (c + 3 < NCHS)      { WAITVM(8); }   // out={c+1,c+2,c+3} -> c+1 landed
    else if (c + 2 < NCHS) { WAITVM(4); }   // out={c+1,c+2}
    else if (c + 1 < NCHS) { WAITVM(0); }   // out={c+1}
    if (c + 1 < NCHS) RBAR();            // union of waves' chunk c+1 complete
  }

  // partial logits [kt][tile][64 tok][64 exp] (C/D: row=(reg&3)+8*(reg>>2)+4*h2)
  float* pp = part + ((size_t)kt * NTILE + blockIdx.x) * 4096;
#pragma unroll
  for (int reg = 0; reg < 16; ++reg) {
    const int rowf = (reg & 3) + 8 * (reg >> 2) + 4 * h2;
    pp[(wm * 32 + rowf) * 64 + we * 32 + r] =
        ((m0[reg] + m1[reg]) + (c0[reg] + c1[reg])) + c2[reg];
  }
}

// ---- stage 2: sum KS partials + bias, top-8 + softmax. 1024 blocks x 64 thr ----
__global__ __launch_bounds__(64)
void reduce_topk_kernel(const float* __restrict__ part,
                        const float* __restrict__ bias,
                        float* __restrict__ out) {
  __shared__ __align__(16) float fin[1024];       // 16 tokens x 64 experts
  const int lane = threadIdx.x;                   // 0..63
  const int g    = blockIdx.x;                    // tokens 16g..16g+15
  const int tile = g >> 2;
  const int rowBase = (g & 3) * 16;

  const int row = lane >> 2;
  const int e0  = (lane & 3) * 16;
  const size_t off0 = (size_t)tile * 4096 + (rowBase + row) * 64 + e0;
  float4 s0 = make_float4(0.f, 0.f, 0.f, 0.f), s1 = s0, s2 = s0, s3 = s0;
#pragma unroll
  for (int kt = 0; kt < KS; ++kt) {
    const float* p = part + (size_t)kt * (NTILE * 4096) + off0;
    const float4 q0 = *(const float4*)(p);
    const float4 q1 = *(const float4*)(p + 4);
    const float4 q2 = *(const float4*)(p + 8);
    const float4 q3 = *(const float4*)(p + 12);
    s0.x += q0.x; s0.y += q0.y; s0.z += q0.z; s0.w += q0.w;
    s1.x += q1.x; s1.y += q1.y; s1.z += q1.z; s1.w += q1.w;
    s2.x += q2.x; s2.y += q2.y; s2.z += q2.z; s2.w += q2.w;
    s3.x += q3.x; s3.y += q3.y; s3.z += q3.z; s3.w += q3.w;
  }
  *(float4*)(&fin[lane * 16])      = s0;
  *(float4*)(&fin[lane * 16 + 4])  = s1;
  *(float4*)(&fin[lane * 16 + 8])  = s2;
  *(float4*)(&fin[lane * 16 + 12]) = s3;
  __syncthreads();

  for (int tt = 0; tt < 16; ++tt) {
    float v = fin[tt * 64 + lane] + bias[lane];   // lane = expert id
    float myval = 0.f, m0 = 0.f;
    int myidx = 0;
#pragma unroll
    for (int k = 0; k < 8; ++k) {
      float bv = v;
      int   bi = lane;
#pragma unroll
      for (int off = 1; off < 64; off <<= 1) {    // argmax, min-index tiebreak
        const float ov = __shfl_xor(bv, off);
        const int   oi = __shfl_xor(bi, off);
        if (ov > bv || (ov == bv && oi < bi)) { bv = ov; bi = oi; }
      }
      if (k == 0) m0 = bv;
      if (lane == k) { myval = bv; myidx = bi; }
      if (lane == bi) v = -FLT_MAX;               // bi is wave-uniform
    }
    const float el = (lane < 8) ? expf(myval - m0) : 0.f;
    float ssum = el;
    ssum += __shfl_xor(ssum, 1);
    ssum += __shfl_xor(ssum, 2);
    ssum += __shfl_xor(ssum, 4);
    if (lane < 8) {
      const size_t tg = (size_t)g * 16 + tt;
      out[tg * 8 + lane] = el / ssum;                        // weights (f32)
      out[(size_t)TOKS * 8 + tg * 8 + lane] = (float)myidx;  // indices as f32
    }
  }
}

extern "C" void kernel_launch(void* const* d_in, const int* in_sizes, int n_in,
                              void* d_out, int out_size, void* d_ws, size_t ws_size,
                              hipStream_t stream) {
  const float* x    = (const float*)d_in[0];
  const float* wgt  = (const float*)d_in[1];
  const float* bias = (const float*)d_in[2];
  float* out  = (float*)d_out;
  float* part = (float*)d_ws;   // KS planes x 4 MiB, then 1.5 MiB w-planes

  unsigned short* wsp = (unsigned short*)((char*)d_ws + (size_t)KS * NTILE * 4096 * sizeof(float));

  hipLaunchKernelGGL(wsplit_kernel, dim3(NEXP * HDIM / (256 * 8)), dim3(256), 0, stream,
                     wgt, wsp);
  hipLaunchKernelGGL(router_mfma_kernel, dim3(NTILE, KS), dim3(256), 0, stream,
                     x, wsp, part);
  hipLaunchKernelGGL(reduce_topk_kernel, dim3(TOKS / 16), dim3(64), 0, stream,
                     part, bias, out);
}